// Round 11
// baseline (267.742 us; speedup 1.0000x reference)
//
#include <hip/hip_runtime.h>
#include <hip/hip_cooperative_groups.h>
#include <cmath>

namespace cg = cooperative_groups;

#define B_ 16
#define H_ 32
#define W_ 32
#define C_ 128
#define F_ 128
#define KSZ (9*C_*F_)        // 147456 elems per expert kernel
#define NKS 36               // K-steps of 32 (9 taps x 4 c-chunks)
#define FRAG_ELE 4096        // elems per K-step fragment chunk

typedef __bf16 bf16;
typedef __bf16 bf16x4 __attribute__((ext_vector_type(4)));
typedef __bf16 bf16x8 __attribute__((ext_vector_type(8)));
typedef float  f32x4  __attribute__((ext_vector_type(4)));

__device__ __forceinline__ float softplus_f(float v) {
  return log1pf(expf(-fabsf(v))) + fmaxf(v, 0.f);
}

// logit for batch bb, expert e from phase-1 partials (16 per batch).
// Bit-identical op order at every call site -> consistent gates everywhere.
__device__ __forceinline__ float logit_f(const float* part, const float* gob,
                                         const float* epsg, int bb, int e) {
  float s = 0.f;
  #pragma unroll
  for (int hb = 0; hb < 16; ++hb) s += part[(bb*16 + hb)*8 + e];
  return s + gob[e] + 1e-4f * epsg[bb*8 + e];
}

// XCD-aware block -> (batch, h-pair): batch b's 16 blocks land on XCD b&7. [T1]
__device__ __forceinline__ void block_map_f(int bid, int* b, int* hb) {
  *b  = (bid & 7) * 2 + (bid >> 7);
  *hb = (bid >> 3) & 15;
}

// ---------------------------------------------------------------------------
// FUSED cooperative kernel, grid 256 x 1024 (1 block/CU, co-resident).
//  phase 0: blocks 0..35 build per-expert bf16 bank (frag order); blocks
//           36..71 convert gk -> bf16 hi/lo (tile aliased on comb); ALL
//           blocks stage x f32->bf16 hi/lo into XOR-swizzled LDS.
//  grid.sync (+threadfence for cross-XCD visibility of bank/bgh/bgl)
//  phase 1: gating conv (split-precision, K-split 2x8 waves, 3-slot reg
//           B-pipeline) + fused 2x2 maxpool + dense -> part[b][hb][8].
//  grid.sync (+threadfence for part)
//  phase 2: gates (recomputed per block, deterministic), top-2 expert bank
//           conv REUSING the still-resident xs hi (comb no longer aliases
//           xs -> no x restage), gate-weighted merge + bias -> out.
// LDS: xs 69632 + comb 32768 + small = ~102.7KB (<160KB, 1 block/CU).
// ---------------------------------------------------------------------------
__global__ __launch_bounds__(1024, 4) void fused_k(
    const float* __restrict__ x,    const float* __restrict__ mu,
    const float* __restrict__ rho,  const float* __restrict__ epsk,
    const float* __restrict__ gk,   const float* __restrict__ gb,
    const float* __restrict__ Wg,   const float* __restrict__ gob,
    const float* __restrict__ epsg, const float* __restrict__ ebias,
    bf16* __restrict__ bank, bf16* __restrict__ bgh, bf16* __restrict__ bgl,
    float* __restrict__ part, float* __restrict__ outv)
{
  cg::grid_group gg = cg::this_grid();
  int b, hb;
  block_map_f(blockIdx.x, &b, &hb);
  const int bid = blockIdx.x;
  const int t   = threadIdx.x;
  const int l   = t & 63;
  const int wid = t >> 6;            // 0..15
  const int kg  = wid >> 3;          // K-group
  const int w8  = wid & 7;

  __shared__ bf16  xs[2*4*34*128];   // 69632 B, swizzled; var0 hi / var1 lo
  __shared__ float comb[8192];       // 32768 B: phase-0 tile + K-combine
  __shared__ float red[8][8];
  __shared__ float gl8[8];
  __shared__ float gw2[2];
  __shared__ int   eid2[2];

  // ================= phase 0: prep + x staging =============================
  if (bid < NKS) {                   // ---- expert bank, ks = bid ----
    if (t < 512) {
      const int ks = bid;
      const int nf = t >> 6;         // 0..7
      const int khkw = ks >> 2, kw = khkw % 3;
      const int f  = nf*16 + (l & 15);
      const int cb = (ks & 3)*32 + (l >> 4)*8;
      bf16x8 ob[8];
      #pragma unroll
      for (int j = 0; j < 8; ++j) {
        const int c = cb + j;
        const float* mp = &mu  [(size_t)((khkw*C_ + c)*F_ + f) * 8];
        const float* ep = &epsk[(size_t)((khkw*C_ + c)*F_ + f) * 8];
        const float* rp = &rho [(size_t)((kw  *C_ + c)*F_ + f) * 8];
        #pragma unroll
        for (int e = 0; e < 8; ++e)
          ob[e][j] = (bf16)(mp[e] + softplus_f(rp[e]) * ep[e]);
      }
      #pragma unroll
      for (int e = 0; e < 8; ++e) {
        size_t o = (size_t)e*KSZ + (size_t)ks*FRAG_ELE + nf*512 + l*8;
        *(bf16x8*)&bank[o] = ob[e];
      }
    }
  } else if (bid < 2*NKS) {          // ---- gk -> bf16 hi/lo frag order ----
    const int ks = bid - NKS;
    const int khkw = ks >> 2, cb = (ks & 3)*32;
    {
      int c  = t >> 5;               // 32 c x 32 f4-chunks = 1024 items
      int f4 = (t & 31) * 4;
      float4 val = *(const float4*)&gk[(size_t)(khkw*C_ + cb + c)*F_ + f4];
      float* dst = &comb[c*129 + f4];
      dst[0]=val.x; dst[1]=val.y; dst[2]=val.z; dst[3]=val.w;
    }
    __syncthreads();
    if (t < 512) {
      const int nf = t >> 6;
      const int f  = nf*16 + (l & 15);
      bf16x8 h8, l8;
      #pragma unroll
      for (int j = 0; j < 8; ++j) {
        int c = (l >> 4)*8 + j;
        float v = comb[c*129 + f];
        bf16 h = (bf16)v;
        h8[j] = h;
        l8[j] = (bf16)(v - (float)h);
      }
      *(bf16x8*)&bgh[(size_t)ks*FRAG_ELE + t*8] = h8;
      *(bf16x8*)&bgl[(size_t)ks*FRAG_ELE + t*8] = l8;
    }
    __syncthreads();                 // comb free again
  }

  // ---- stage x (4 rows x 34 cols x 128c), f32 -> bf16 hi/lo, swizzled ----
  for (int v = t; v < 4*34*32; v += 1024) {
    int c4   = v & 31;
    int col  = (v >> 5) % 34;
    int rowi = (v >> 5) / 34;
    int row  = hb*2 - 1 + rowi;
    int w    = col - 1;
    float4 xv = make_float4(0.f, 0.f, 0.f, 0.f);
    if (row >= 0 && row < H_ && w >= 0 && w < W_)
      xv = *(const float4*)&x[((b*H_ + row)*W_ + w)*C_ + c4*4];
    float vv[4] = {xv.x, xv.y, xv.z, xv.w};
    bf16x4 h4, l4;
    #pragma unroll
    for (int j = 0; j < 4; ++j) {
      h4[j] = (bf16)vv[j];
      l4[j] = (bf16)(vv[j] - (float)h4[j]);
    }
    int base = ((rowi*34 + col)*256 + c4*8) ^ ((col & 7) << 4);
    *(bf16x4*)((char*)xs + base) = h4;
    *(bf16x4*)((char*)xs + 34816 + base) = l4;
  }

  __threadfence();                   // push bank/bgh/bgl to device scope
  gg.sync();

  const int mpar = w8 & 1;           // w-half
  const int nf0  = (w8 >> 1) << 1;   // n-frags nf0, nf0+1
  const int r15  = l & 15;
  const int q    = l >> 4;
  const int ks0  = kg * (NKS/2);

#define MFMA16(a, bb_, c) __builtin_amdgcn_mfma_f32_16x16x32_bf16(a, bb_, c, 0, 0, 0)

#define LOADB(S, KS_) do {                                                  \
    int kk_ = (KS_); if (kk_ > NKS-1) kk_ = NKS-1;                          \
    size_t o_ = bgo + (size_t)kk_ * FRAG_ELE;                               \
    S##h0 = *(const bf16x8*)(B0 + o_);                                      \
    S##h1 = *(const bf16x8*)(B0 + o_ + 512);                                \
    S##l0 = *(const bf16x8*)(B1 + o_);                                      \
    S##l1 = *(const bf16x8*)(B1 + o_ + 512);                                \
  } while (0)

#define AOFF(KS_)                                                           \
    const int khkw_ = (KS_) >> 2;                                           \
    const int kh_ = khkw_ / 3, kw_ = khkw_ % 3;                             \
    const int c0_ = ((KS_) & 3) << 5;                                       \
    const int col_ = mpar*16 + r15 + kw_;                                   \
    const int off_ = ((kh_*34 + col_)*256 + (c0_ + q*8)*2) ^ ((col_ & 7) << 4);

  // ================= phase 1: gating conv ==================================
  {
    f32x4 acc00 = {0.f,0.f,0.f,0.f}, acc01 = acc00, acc10 = acc00, acc11 = acc00;
    const bf16* B0 = bgh;
    const bf16* B1 = bgl;
    const size_t bgo = (size_t)(nf0*512 + l*8);
    bf16x8 s0h0,s0h1,s0l0,s0l1, s1h0,s1h1,s1l0,s1l1, s2h0,s2h1,s2l0,s2l1;

#define COMPUTE2(S, KS_) do {                                               \
    AOFF(KS_)                                                               \
    bf16x8 a0_ = *(const bf16x8*)((const char*)xs + off_);                  \
    bf16x8 a1_ = *(const bf16x8*)((const char*)xs + off_ + 8704);           \
    bf16x8 g0_ = *(const bf16x8*)((const char*)xs + 34816 + off_);          \
    bf16x8 g1_ = *(const bf16x8*)((const char*)xs + 34816 + off_ + 8704);   \
    __builtin_amdgcn_s_setprio(1);                                          \
    acc00 = MFMA16(a0_, S##h0, acc00);                                      \
    acc01 = MFMA16(a0_, S##h1, acc01);                                      \
    acc10 = MFMA16(a1_, S##h0, acc10);                                      \
    acc11 = MFMA16(a1_, S##h1, acc11);                                      \
    acc00 = MFMA16(g0_, S##h0, acc00);                                      \
    acc01 = MFMA16(g0_, S##h1, acc01);                                      \
    acc10 = MFMA16(g1_, S##h0, acc10);                                      \
    acc11 = MFMA16(g1_, S##h1, acc11);                                      \
    acc00 = MFMA16(a0_, S##l0, acc00);                                      \
    acc01 = MFMA16(a0_, S##l1, acc01);                                      \
    acc10 = MFMA16(a1_, S##l0, acc10);                                      \
    acc11 = MFMA16(a1_, S##l1, acc11);                                      \
    __builtin_amdgcn_s_setprio(0);                                          \
  } while (0)

    LOADB(s0, ks0); LOADB(s1, ks0+1); LOADB(s2, ks0+2);
    for (int ks = ks0; ks < ks0 + NKS/2; ks += 3) {
      COMPUTE2(s0, ks);   LOADB(s0, ks+3);
      COMPUTE2(s1, ks+1); LOADB(s1, ks+4);
      COMPUTE2(s2, ks+2); LOADB(s2, ks+5);
    }
#undef COMPUTE2

    // combine K-group partials via comb
    __syncthreads();
    if (kg == 1) {
      #pragma unroll
      for (int r = 0; r < 4; ++r) {
        comb[(w8*16 + 0  + r)*64 + l] = acc00[r];
        comb[(w8*16 + 4  + r)*64 + l] = acc01[r];
        comb[(w8*16 + 8  + r)*64 + l] = acc10[r];
        comb[(w8*16 + 12 + r)*64 + l] = acc11[r];
      }
    }
    __syncthreads();
    if (kg == 0) {
      #pragma unroll
      for (int r = 0; r < 4; ++r) {
        acc00[r] += comb[(w8*16 + 0  + r)*64 + l];
        acc01[r] += comb[(w8*16 + 4  + r)*64 + l];
        acc10[r] += comb[(w8*16 + 8  + r)*64 + l];
        acc11[r] += comb[(w8*16 + 12 + r)*64 + l];
      }
    }

    // fused 2x2 maxpool + dense partials
    float pr[8] = {0,0,0,0,0,0,0,0};
    if (kg == 0) {
      #pragma unroll
      for (int ni = 0; ni < 2; ++ni) {
        const int f = (nf0 + ni)*16 + r15;
        const float bv = gb[f];
        #pragma unroll
        for (int pp = 0; pp < 2; ++pp) {
          float m0 = ni ? fmaxf(acc01[2*pp], acc01[2*pp+1])
                        : fmaxf(acc00[2*pp], acc00[2*pp+1]);
          float m1 = ni ? fmaxf(acc11[2*pp], acc11[2*pp+1])
                        : fmaxf(acc10[2*pp], acc10[2*pp+1]);
          float pm = fmaxf(m0, m1) + bv;
          const int pw = mpar*8 + q*2 + pp;
          const float* wr = &Wg[(size_t)((hb*16 + pw)*128 + f) * 8];
          float4 wA = *(const float4*)wr;
          float4 wB = *(const float4*)(wr + 4);
          pr[0] += pm*wA.x; pr[1] += pm*wA.y; pr[2] += pm*wA.z; pr[3] += pm*wA.w;
          pr[4] += pm*wB.x; pr[5] += pm*wB.y; pr[6] += pm*wB.z; pr[7] += pm*wB.w;
        }
      }
    }
    #pragma unroll
    for (int o = 32; o > 0; o >>= 1)
      #pragma unroll
      for (int e = 0; e < 8; ++e) pr[e] += __shfl_down(pr[e], o);
    if (l == 0 && kg == 0)
      #pragma unroll
      for (int e = 0; e < 8; ++e) red[w8][e] = pr[e];
    __syncthreads();
    if (t < 8) {
      float s = 0.f;
      #pragma unroll
      for (int w = 0; w < 8; ++w) s += red[w][t];
      part[(b*16 + hb)*8 + t] = s;   // partial logits
    }
  }

  __threadfence();                   // push part to device scope
  gg.sync();

  // ================= phase 2: expert conv (top-2 bank) =====================
  if (t == 0) {                      // gates for this batch (deterministic)
    float lg[8];
    #pragma unroll
    for (int e = 0; e < 8; ++e) lg[e] = logit_f(part, gob, epsg, b, e);
    int i0 = 0;
    #pragma unroll
    for (int e = 1; e < 8; ++e) if (lg[e] > lg[i0]) i0 = e;
    int i1 = (i0 == 0) ? 1 : 0;
    #pragma unroll
    for (int e = 0; e < 8; ++e) if (e != i0 && lg[e] > lg[i1]) i1 = e;
    float m  = fmaxf(lg[i0], lg[i1]);
    float e0 = expf(lg[i0] - m), e1 = expf(lg[i1] - m);
    float s  = e0 + e1;
    #pragma unroll
    for (int e = 0; e < 8; ++e) gl8[e] = 0.f;
    gl8[i0] = e0 / s;  gl8[i1] = e1 / s;
    eid2[0] = i0;      eid2[1] = i1;
    gw2[0]  = e0 / s;  gw2[1]  = e1 / s;
  }
  __syncthreads();

  {
    f32x4 acc00 = {0.f,0.f,0.f,0.f}, acc01 = acc00, acc10 = acc00, acc11 = acc00;
    f32x4 acd00 = acc00, acd01 = acc00, acd10 = acc00, acd11 = acc00;
    const bf16* B0 = bank + (size_t)eid2[0]*KSZ;
    const bf16* B1 = bank + (size_t)eid2[1]*KSZ;
    const size_t bgo = (size_t)(nf0*512 + l*8);
    bf16x8 s0h0,s0h1,s0l0,s0l1, s1h0,s1h1,s1l0,s1l1, s2h0,s2h1,s2l0,s2l1;

#define COMPUTE1(S, KS_) do {                                               \
    AOFF(KS_)                                                               \
    bf16x8 a0_ = *(const bf16x8*)((const char*)xs + off_);                  \
    bf16x8 a1_ = *(const bf16x8*)((const char*)xs + off_ + 8704);           \
    __builtin_amdgcn_s_setprio(1);                                          \
    acc00 = MFMA16(a0_, S##h0, acc00);                                      \
    acc01 = MFMA16(a0_, S##h1, acc01);                                      \
    acc10 = MFMA16(a1_, S##h0, acc10);                                      \
    acc11 = MFMA16(a1_, S##h1, acc11);                                      \
    acd00 = MFMA16(a0_, S##l0, acd00);                                      \
    acd01 = MFMA16(a0_, S##l1, acd01);                                      \
    acd10 = MFMA16(a1_, S##l0, acd10);                                      \
    acd11 = MFMA16(a1_, S##l1, acd11);                                      \
    __builtin_amdgcn_s_setprio(0);                                          \
  } while (0)

    LOADB(s0, ks0); LOADB(s1, ks0+1); LOADB(s2, ks0+2);
    for (int ks = ks0; ks < ks0 + NKS/2; ks += 3) {
      COMPUTE1(s0, ks);   LOADB(s0, ks+3);
      COMPUTE1(s1, ks+1); LOADB(s1, ks+4);
      COMPUTE1(s2, ks+2); LOADB(s2, ks+5);
    }
#undef COMPUTE1

    // gate-weighted merge (linear in K -> valid per K-group partial)
    const float g0 = gw2[0], g1 = gw2[1];
    #pragma unroll
    for (int r = 0; r < 4; ++r) {
      acc00[r] = g0*acc00[r] + g1*acd00[r];
      acc01[r] = g0*acc01[r] + g1*acd01[r];
      acc10[r] = g0*acc10[r] + g1*acd10[r];
      acc11[r] = g0*acc11[r] + g1*acd11[r];
    }

    // combine K-group partials via comb
    __syncthreads();
    if (kg == 1) {
      #pragma unroll
      for (int r = 0; r < 4; ++r) {
        comb[(w8*16 + 0  + r)*64 + l] = acc00[r];
        comb[(w8*16 + 4  + r)*64 + l] = acc01[r];
        comb[(w8*16 + 8  + r)*64 + l] = acc10[r];
        comb[(w8*16 + 12 + r)*64 + l] = acc11[r];
      }
    }
    __syncthreads();
    if (kg == 0) {
      #pragma unroll
      for (int r = 0; r < 4; ++r) {
        acc00[r] += comb[(w8*16 + 0  + r)*64 + l];
        acc01[r] += comb[(w8*16 + 4  + r)*64 + l];
        acc10[r] += comb[(w8*16 + 8  + r)*64 + l];
        acc11[r] += comb[(w8*16 + 12 + r)*64 + l];
      }
      const int f0 = nf0*16 + r15;
      float bv0 = 0.f, bv1 = 0.f;
      #pragma unroll
      for (int e = 0; e < 8; ++e) {
        bv0 += gl8[e] * ebias[f0*8 + e];
        bv1 += gl8[e] * ebias[(f0+16)*8 + e];
      }
      #pragma unroll
      for (int mi = 0; mi < 2; ++mi) {
        const int h = hb*2 + mi;
        #pragma unroll
        for (int r = 0; r < 4; ++r) {
          const int wo = mpar*16 + q*4 + r;
          float* o = &outv[((b*H_ + h)*W_ + wo)*F_];
          o[f0]      = (mi ? acc10[r] : acc00[r]) + bv0;
          o[f0 + 16] = (mi ? acc11[r] : acc01[r]) + bv1;
        }
      }
    }
  }
#undef LOADB
#undef AOFF
#undef MFMA16
}

// ---------------------------------------------------------------------------
extern "C" void kernel_launch(void* const* d_in, const int* in_sizes, int n_in,
                              void* d_out, int out_size, void* d_ws, size_t ws_size,
                              hipStream_t stream) {
  const float* x    = (const float*)d_in[0];
  const float* epsk = (const float*)d_in[1];
  const float* epsg = (const float*)d_in[2];
  const float* mu   = (const float*)d_in[3];
  const float* rho  = (const float*)d_in[4];
  const float* ebias= (const float*)d_in[5];
  const float* gk   = (const float*)d_in[6];
  const float* gb   = (const float*)d_in[7];
  const float* gok  = (const float*)d_in[8];
  const float* gob  = (const float*)d_in[9];
  float* out = (float*)d_out;

  char* ws = (char*)d_ws;
  bf16*  bank = (bf16*) (ws);                   // 2,359,296 B (8 experts)
  bf16*  bgh  = (bf16*) (ws + 2359296);         //   294,912 B
  bf16*  bgl  = (bf16*) (ws + 2654208);         //   294,912 B
  float* part = (float*)(ws + 2949120);         //     8,192 B  (~3 MB)

  void* args[] = {
    (void*)&x,    (void*)&mu,   (void*)&rho,  (void*)&epsk, (void*)&gk,
    (void*)&gb,   (void*)&gok,  (void*)&gob,  (void*)&epsg, (void*)&ebias,
    (void*)&bank, (void*)&bgh,  (void*)&bgl,  (void*)&part, (void*)&out,
  };
  hipLaunchCooperativeKernel(fused_k, dim3(256), dim3(1024), args, 0, stream);
}

// Round 12
// 54.855 us; speedup vs baseline: 4.8809x; 4.8809x over previous
//
#include <hip/hip_runtime.h>
#include <cmath>

#define B_ 16
#define H_ 32
#define W_ 32
#define C_ 128
#define F_ 128
#define KSZ (9*C_*F_)        // 147456 elems per expert kernel
#define NKS 36               // K-steps of 32 (9 taps x 4 c-chunks)
#define FRAG_ELE 4096        // elems per K-step fragment chunk

typedef __bf16 bf16;
typedef __bf16 bf16x4 __attribute__((ext_vector_type(4)));
typedef __bf16 bf16x8 __attribute__((ext_vector_type(8)));
typedef float  f32x4  __attribute__((ext_vector_type(4)));

__device__ __forceinline__ float softplus_f(float v) {
  return log1pf(expf(-fabsf(v))) + fmaxf(v, 0.f);
}

// logit for batch bb, expert e from conv<2> partials (16 per batch).
// Bit-identical op order at every call site -> consistent gates everywhere.
__device__ __forceinline__ float logit_f(const float* part, const float* gob,
                                         const float* epsg, int bb, int e) {
  float s = 0.f;
  #pragma unroll
  for (int hb = 0; hb < 16; ++hb) s += part[(bb*16 + hb)*8 + e];
  return s + gob[e] + 1e-4f * epsg[bb*8 + e];
}

// XCD-aware block -> (batch, h-pair): batch b's 16 blocks land on one XCD. [T1]
__device__ __forceinline__ void block_map_f(int bid, int* b, int* hb) {
  *b  = (bid & 7) * 2 + (bid >> 7);
  *hb = (bid >> 3) & 15;
}

// ---------------------------------------------------------------------------
// MFMA 3x3 SAME conv, block = (b, h-pair): M=64 (2h x 32w), N=128, K=1152.
// 1024 threads = 16 waves, K-SPLIT (kg=0: ks 0..17, kg=1: 18..35), partial
// accs combined via LDS (aliased over dead xs). r10 structure verbatim.
// B: fragment-ordered global, 3-slot register pipeline (DEP=3 proven
//    no-spill at the 128-VGPR allocation; 4-6 deep spilled in r4/r5).
// MODE==2: grid NKS+256. Blocks 0..NKS-1 BUILD THE EXPERT BANK (gate-
//          independent work overlapped with the conv instead of serialized
//          in prep — r10's lesson applied again) and exit. Blocks NKS..
//          NKS+255: gating conv, split-precision (Ah*Bh + Al*Bh + Ah*Bl),
//          epilogue fuses 2x2 maxpool + dense partials -> part[b][hb][8].
// MODE==1: expert conv via TOP-2 BANK: B0/B1 = the two selected experts'
//          banks, dual acc sets, merge out = g0*accA + g1*accB + bias.
// ---------------------------------------------------------------------------
template<int MODE>
__global__ __launch_bounds__(1024, 4) void conv_k(
    const float* __restrict__ x,
    const bf16* __restrict__ Bhi,    // MODE2: gk-hi frags; MODE1: expert bank
    const bf16* __restrict__ Blo,    // MODE2: gk-lo frags; MODE1: unused
    const float* __restrict__ gb,    // gating conv bias     (MODE==2)
    const float* __restrict__ Wg,    // gating dense weights (MODE==2)
    const float* __restrict__ part,  // logit partials       (MODE==1)
    const float* __restrict__ gob,   // gating out bias      (MODE==1)
    const float* __restrict__ epsg,  // gate noise           (MODE==1)
    const float* __restrict__ ebias, // expert bias [F][8]   (MODE==1)
    const float* __restrict__ mu,    // bank build           (MODE==2)
    const float* __restrict__ rho,   // bank build           (MODE==2)
    const float* __restrict__ epsk,  // bank build           (MODE==2)
    bf16* __restrict__ bank,         // bank build out       (MODE==2)
    float* __restrict__ outv)
{
  const int t   = threadIdx.x;
  const int l   = t & 63;

  // ---- MODE2 leading blocks: per-expert bf16 bank in fragment order ----
  if (MODE == 2 && blockIdx.x < NKS) {
    if (t < 512) {
      const int ks = blockIdx.x;
      const int nf = t >> 6;         // 0..7
      const int khkw = ks >> 2, kw = khkw % 3;
      const int f  = nf*16 + (l & 15);
      const int cb = (ks & 3)*32 + (l >> 4)*8;
      bf16x8 ob[8];
      #pragma unroll
      for (int j = 0; j < 8; ++j) {
        const int c = cb + j;
        const float* mp = &mu  [(size_t)((khkw*C_ + c)*F_ + f) * 8];
        const float* ep = &epsk[(size_t)((khkw*C_ + c)*F_ + f) * 8];
        const float* rp = &rho [(size_t)((kw  *C_ + c)*F_ + f) * 8];
        #pragma unroll
        for (int e = 0; e < 8; ++e)
          ob[e][j] = (bf16)(mp[e] + softplus_f(rp[e]) * ep[e]);
      }
      #pragma unroll
      for (int e = 0; e < 8; ++e) {
        size_t o = (size_t)e*KSZ + (size_t)ks*FRAG_ELE + nf*512 + l*8;
        *(bf16x8*)&bank[o] = ob[e];
      }
    }
    return;
  }

  int b, hb;
  block_map_f(MODE == 2 ? blockIdx.x - NKS : blockIdx.x, &b, &hb);
  const int wid = t >> 6;            // 0..15
  const int kg  = wid >> 3;          // K-group
  const int w8  = wid & 7;

  __shared__ bf16 xs[MODE*4*34*128]; // 34816 B per variant, swizzled
  __shared__ float red[8][8];
  __shared__ float gl8[8];
  __shared__ float gw2[2];
  __shared__ int   eid2[2];

  // ---- stage x (4 rows x 34 cols x 128c), f32 -> bf16 hi(/lo), swizzled ----
  for (int v = t; v < 4*34*32; v += 1024) {
    int c4   = v & 31;
    int col  = (v >> 5) % 34;
    int rowi = (v >> 5) / 34;
    int row  = hb*2 - 1 + rowi;
    int w    = col - 1;
    float4 xv = make_float4(0.f, 0.f, 0.f, 0.f);
    if (row >= 0 && row < H_ && w >= 0 && w < W_)
      xv = *(const float4*)&x[((b*H_ + row)*W_ + w)*C_ + c4*4];
    float vv[4] = {xv.x, xv.y, xv.z, xv.w};
    bf16x4 h4, l4;
    #pragma unroll
    for (int j = 0; j < 4; ++j) {
      h4[j] = (bf16)vv[j];
      if (MODE == 2) l4[j] = (bf16)(vv[j] - (float)h4[j]);
    }
    int base = ((rowi*34 + col)*256 + c4*8) ^ ((col & 7) << 4);
    *(bf16x4*)((char*)xs + base) = h4;
    if (MODE == 2) *(bf16x4*)((char*)xs + 34816 + base) = l4;
  }
  if (MODE == 1 && t == 0) {         // gates + top-2 ids for this batch
    float lg[8];
    #pragma unroll
    for (int e = 0; e < 8; ++e) lg[e] = logit_f(part, gob, epsg, b, e);
    int i0 = 0;
    #pragma unroll
    for (int e = 1; e < 8; ++e) if (lg[e] > lg[i0]) i0 = e;
    int i1 = (i0 == 0) ? 1 : 0;
    #pragma unroll
    for (int e = 0; e < 8; ++e) if (e != i0 && lg[e] > lg[i1]) i1 = e;
    float m  = fmaxf(lg[i0], lg[i1]);
    float e0 = expf(lg[i0] - m), e1 = expf(lg[i1] - m);
    float s  = e0 + e1;
    #pragma unroll
    for (int e = 0; e < 8; ++e) gl8[e] = 0.f;
    gl8[i0] = e0 / s;  gl8[i1] = e1 / s;
    eid2[0] = i0;      eid2[1] = i1;
    gw2[0]  = e0 / s;  gw2[1]  = e1 / s;
  }
  __syncthreads();

  const int mpar = w8 & 1;             // w-half
  const int nf0  = (w8 >> 1) << 1;     // n-frags nf0, nf0+1
  const int r15  = l & 15;
  const int q    = l >> 4;

  f32x4 acc00 = {0.f,0.f,0.f,0.f}, acc01 = acc00, acc10 = acc00, acc11 = acc00;
  f32x4 acd00 = acc00, acd01 = acc00, acd10 = acc00, acd11 = acc00; // MODE1: expert B

  const bf16* B0;
  const bf16* B1;
  if (MODE == 1) { B0 = Bhi + (size_t)eid2[0]*KSZ; B1 = Bhi + (size_t)eid2[1]*KSZ; }
  else           { B0 = Bhi;                       B1 = Blo; }
  const size_t bgo = (size_t)(nf0*512 + l*8);

  bf16x8 s0h0,s0h1,s0l0,s0l1, s1h0,s1h1,s1l0,s1l1, s2h0,s2h1,s2l0,s2l1;

#define LOADB(S, KS_) do {                                                  \
    int kk_ = (KS_); if (kk_ > NKS-1) kk_ = NKS-1;                          \
    size_t o_ = bgo + (size_t)kk_ * FRAG_ELE;                               \
    S##h0 = *(const bf16x8*)(B0 + o_);                                      \
    S##h1 = *(const bf16x8*)(B0 + o_ + 512);                                \
    S##l0 = *(const bf16x8*)(B1 + o_);                                      \
    S##l1 = *(const bf16x8*)(B1 + o_ + 512);                                \
  } while (0)

#define MFMA16(a, bb_, c) __builtin_amdgcn_mfma_f32_16x16x32_bf16(a, bb_, c, 0, 0, 0)

#define COMPUTE(S, KS_) do {                                                \
    const int khkw_ = (KS_) >> 2;                                           \
    const int kh_ = khkw_ / 3, kw_ = khkw_ % 3;                             \
    const int c0_ = ((KS_) & 3) << 5;                                       \
    const int col_ = mpar*16 + r15 + kw_;                                   \
    const int off_ = ((kh_*34 + col_)*256 + (c0_ + q*8)*2) ^ ((col_ & 7) << 4); \
    bf16x8 a0_ = *(const bf16x8*)((const char*)xs + off_);                  \
    bf16x8 a1_ = *(const bf16x8*)((const char*)xs + off_ + 8704);           \
    __builtin_amdgcn_s_setprio(1);                                          \
    acc00 = MFMA16(a0_, S##h0, acc00);                                      \
    acc01 = MFMA16(a0_, S##h1, acc01);                                      \
    acc10 = MFMA16(a1_, S##h0, acc10);                                      \
    acc11 = MFMA16(a1_, S##h1, acc11);                                      \
    if (MODE == 2) {                                                        \
      bf16x8 g0_ = *(const bf16x8*)((const char*)xs + 34816 + off_);        \
      bf16x8 g1_ = *(const bf16x8*)((const char*)xs + 34816 + off_ + 8704); \
      acc00 = MFMA16(g0_, S##h0, acc00);                                    \
      acc01 = MFMA16(g0_, S##h1, acc01);                                    \
      acc10 = MFMA16(g1_, S##h0, acc10);                                    \
      acc11 = MFMA16(g1_, S##h1, acc11);                                    \
      acc00 = MFMA16(a0_, S##l0, acc00);                                    \
      acc01 = MFMA16(a0_, S##l1, acc01);                                    \
      acc10 = MFMA16(a1_, S##l0, acc10);                                    \
      acc11 = MFMA16(a1_, S##l1, acc11);                                    \
    } else {                                                                \
      acd00 = MFMA16(a0_, S##l0, acd00);                                    \
      acd01 = MFMA16(a0_, S##l1, acd01);                                    \
      acd10 = MFMA16(a1_, S##l0, acd10);                                    \
      acd11 = MFMA16(a1_, S##l1, acd11);                                    \
    }                                                                       \
    __builtin_amdgcn_s_setprio(0);                                          \
  } while (0)

  const int ks0 = kg * (NKS/2);
  LOADB(s0, ks0); LOADB(s1, ks0+1); LOADB(s2, ks0+2);
  for (int ks = ks0; ks < ks0 + NKS/2; ks += 3) {
    COMPUTE(s0, ks);   LOADB(s0, ks+3);
    COMPUTE(s1, ks+1); LOADB(s1, ks+4);
    COMPUTE(s2, ks+2); LOADB(s2, ks+5);
  }
#undef LOADB
#undef COMPUTE

  // ---- MODE1: gate-weighted merge of the two expert accs (linear in K) ----
  if (MODE == 1) {
    const float g0 = gw2[0], g1 = gw2[1];
    #pragma unroll
    for (int r = 0; r < 4; ++r) {
      acc00[r] = g0*acc00[r] + g1*acd00[r];
      acc01[r] = g0*acc01[r] + g1*acd01[r];
      acc10[r] = g0*acc10[r] + g1*acd10[r];
      acc11[r] = g0*acc11[r] + g1*acd11[r];
    }
  }

  // ---- combine K-group partial accumulators via LDS (aliased over xs) ----
  __syncthreads();                       // all xs reads done
  float* comb = (float*)xs;              // [8 w8][16 i][64 l] = 32KB
  if (kg == 1) {
    #pragma unroll
    for (int r = 0; r < 4; ++r) {
      comb[(w8*16 + 0  + r)*64 + l] = acc00[r];
      comb[(w8*16 + 4  + r)*64 + l] = acc01[r];
      comb[(w8*16 + 8  + r)*64 + l] = acc10[r];
      comb[(w8*16 + 12 + r)*64 + l] = acc11[r];
    }
  }
  __syncthreads();
  if (kg == 0) {
    #pragma unroll
    for (int r = 0; r < 4; ++r) {
      acc00[r] += comb[(w8*16 + 0  + r)*64 + l];
      acc01[r] += comb[(w8*16 + 4  + r)*64 + l];
      acc10[r] += comb[(w8*16 + 8  + r)*64 + l];
      acc11[r] += comb[(w8*16 + 12 + r)*64 + l];
    }
  }

  // C/D layout: col(f) = l&15, row(m within frag) = q*4 + r
  if (MODE == 1) {
    if (kg == 0) {
      const int f0 = nf0*16 + r15;
      float bv0 = 0.f, bv1 = 0.f;
      #pragma unroll
      for (int e = 0; e < 8; ++e) {
        bv0 += gl8[e] * ebias[f0*8 + e];
        bv1 += gl8[e] * ebias[(f0+16)*8 + e];
      }
      #pragma unroll
      for (int mi = 0; mi < 2; ++mi) {
        const int h = hb*2 + mi;
        #pragma unroll
        for (int r = 0; r < 4; ++r) {
          const int wo = mpar*16 + q*4 + r;
          float* o = &outv[((b*H_ + h)*W_ + wo)*F_];
          o[f0]      = (mi ? acc10[r] : acc00[r]) + bv0;
          o[f0 + 16] = (mi ? acc11[r] : acc01[r]) + bv1;
        }
      }
    }
  } else {
    float pr[8] = {0,0,0,0,0,0,0,0};
    if (kg == 0) {
      #pragma unroll
      for (int ni = 0; ni < 2; ++ni) {
        const int f = (nf0 + ni)*16 + r15;
        const float bv = gb[f];
        #pragma unroll
        for (int pp = 0; pp < 2; ++pp) {
          float m0 = ni ? fmaxf(acc01[2*pp], acc01[2*pp+1])
                        : fmaxf(acc00[2*pp], acc00[2*pp+1]);
          float m1 = ni ? fmaxf(acc11[2*pp], acc11[2*pp+1])
                        : fmaxf(acc10[2*pp], acc10[2*pp+1]);
          float pm = fmaxf(m0, m1) + bv;
          const int pw = mpar*8 + q*2 + pp;
          const float* wr = &Wg[(size_t)((hb*16 + pw)*128 + f) * 8];
          float4 wA = *(const float4*)wr;
          float4 wB = *(const float4*)(wr + 4);
          pr[0] += pm*wA.x; pr[1] += pm*wA.y; pr[2] += pm*wA.z; pr[3] += pm*wA.w;
          pr[4] += pm*wB.x; pr[5] += pm*wB.y; pr[6] += pm*wB.z; pr[7] += pm*wB.w;
        }
      }
    }
    #pragma unroll
    for (int o = 32; o > 0; o >>= 1)
      #pragma unroll
      for (int e = 0; e < 8; ++e) pr[e] += __shfl_down(pr[e], o);
    if (l == 0 && kg == 0)
      #pragma unroll
      for (int e = 0; e < 8; ++e) red[w8][e] = pr[e];
    __syncthreads();
    if (t < 8) {
      float s = 0.f;
      #pragma unroll
      for (int w = 0; w < 8; ++w) s += red[w][t];
      outv[(b*16 + hb)*8 + t] = s;   // partial logits (16 per batch)
    }
  }
}

// ---------------------------------------------------------------------------
// gating_kernel f32 -> bf16 hi/lo in fragment order, via coalesced tile load
// + LDS transpose (stride 129: conflict-free reads). Block = one K-step.
// Tiny (36 blocks) — the only truly serial prep left.
// ---------------------------------------------------------------------------
__global__ __launch_bounds__(1024) void gkprep_k(
    const float* __restrict__ gk, bf16* __restrict__ bgh, bf16* __restrict__ bgl)
{
  __shared__ float tile[32*129];
  const int ks   = blockIdx.x;
  const int khkw = ks >> 2;
  const int cb   = (ks & 3)*32;
  const int t    = threadIdx.x;

  {                                    // 32c x 32 f4-chunks = 1024 items
    int c  = t >> 5;
    int f4 = (t & 31) * 4;
    float4 val = *(const float4*)&gk[(size_t)(khkw*C_ + cb + c)*F_ + f4];
    float* dst = &tile[c*129 + f4];
    dst[0] = val.x; dst[1] = val.y; dst[2] = val.z; dst[3] = val.w;
  }
  __syncthreads();

  if (t < 512) {
    const int nf = t >> 6, l = t & 63;
    const int f  = nf*16 + (l & 15);
    bf16x8 h8, l8;
    #pragma unroll
    for (int j = 0; j < 8; ++j) {
      int c = (l >> 4)*8 + j;
      float v = tile[c*129 + f];
      bf16 h = (bf16)v;
      h8[j] = h;
      l8[j] = (bf16)(v - (float)h);
    }
    *(bf16x8*)&bgh[(size_t)ks*FRAG_ELE + t*8] = h8;
    *(bf16x8*)&bgl[(size_t)ks*FRAG_ELE + t*8] = l8;
  }
}

// ---------------------------------------------------------------------------
extern "C" void kernel_launch(void* const* d_in, const int* in_sizes, int n_in,
                              void* d_out, int out_size, void* d_ws, size_t ws_size,
                              hipStream_t stream) {
  const float* x    = (const float*)d_in[0];
  const float* epsk = (const float*)d_in[1];
  const float* epsg = (const float*)d_in[2];
  const float* mu   = (const float*)d_in[3];
  const float* rho  = (const float*)d_in[4];
  const float* ebias= (const float*)d_in[5];
  const float* gk   = (const float*)d_in[6];
  const float* gb   = (const float*)d_in[7];
  const float* gok  = (const float*)d_in[8];
  const float* gob  = (const float*)d_in[9];
  float* out = (float*)d_out;

  char* ws = (char*)d_ws;
  bf16*  bank = (bf16*) (ws);                   // 2,359,296 B (8 experts)
  bf16*  bgh  = (bf16*) (ws + 2359296);         //   294,912 B
  bf16*  bgl  = (bf16*) (ws + 2654208);         //   294,912 B
  float* part = (float*)(ws + 2949120);         //     8,192 B  (~3 MB)

  // 1. tiny prep: gk -> bf16 hi/lo fragment order
  gkprep_k<<<NKS, 1024, 0, stream>>>(gk, bgh, bgl);
  // 2. gating conv + OVERLAPPED expert-bank build (blocks 0..35)
  conv_k<2><<<NKS + 256, 1024, 0, stream>>>(x, bgh, bgl, gb, gok,
                                            nullptr, nullptr, nullptr, nullptr,
                                            mu, rho, epsk, bank, part);
  // 3. expert conv: top-2 bank conv, gates + weighted merge in-block
  conv_k<1><<<256, 1024, 0, stream>>>(x, bank, nullptr, nullptr, nullptr,
                                      part, gob, epsg, ebias,
                                      nullptr, nullptr, nullptr, nullptr, out);
}